// Round 6
// baseline (145.426 us; speedup 1.0000x reference)
//
#include <hip/hip_runtime.h>
#include <hip/hip_bf16.h>

#define DM 1024
#define SD 32
#define NG 8
#define GD 128
#define BS 4
#define TT 4096
#define CL 64        // chunk length
#define NC (TT/CL)   // 64 chunks
#define NCHAIN (BS*NG)

typedef __attribute__((ext_vector_type(8))) short short8;
typedef __attribute__((ext_vector_type(4))) float f32x4;

// workspace layout (bytes)
#define WS_AGG  0                               // f32[NCHAIN][NC][SD] = 256KB chunk aggregates
#define WS_FLG  (WS_AGG + NCHAIN*NC*SD*4)       // u32[NCHAIN][NC] = 8KB flags (zeroed per call)

__device__ __forceinline__ unsigned short f2bf(float f) {
  __hip_bfloat16 h = __float2bfloat16(f);
  return __builtin_bit_cast(unsigned short, h);
}
__device__ __forceinline__ float bf2f(unsigned short h) {
  return __uint_as_float(((unsigned)h) << 16);
}
__device__ __forceinline__ float softplus_f(float x) {
  return (x > 20.f) ? x : log1pf(expf(x));
}
__device__ __forceinline__ short8 pack8(float4 a, float4 b) {
  short8 h;
  h[0]=(short)f2bf(a.x); h[1]=(short)f2bf(a.y); h[2]=(short)f2bf(a.z); h[3]=(short)f2bf(a.w);
  h[4]=(short)f2bf(b.x); h[5]=(short)f2bf(b.y); h[6]=(short)f2bf(b.z); h[7]=(short)f2bf(b.w);
  return h;
}

// ---------------- fused: Bu GEMM + local scan + carry-passing + C GEMM + y ----------------
__global__ __launch_bounds__(64) void fused_s5(const float* __restrict__ u,
                                               const float* __restrict__ state0,
                                               const float* __restrict__ A_log,
                                               const float* __restrict__ B_param,
                                               const float* __restrict__ C,
                                               const float* __restrict__ Dp,
                                               const float* __restrict__ dt_logit,
                                               unsigned char* __restrict__ ws,
                                               float* __restrict__ y,
                                               float* __restrict__ sfin) {
  const int bx = blockIdx.x;
  const int c = bx & (NC - 1);
  const int g = (bx >> 6) & (NG - 1);
  const int b = bx >> 9;
  const int chain = b * NG + g;
  const int l = threadIdx.x;
  const int lr = l & 15, lh = l >> 4;
  const int n = l & 31;

  float* agg = (float*)(ws + WS_AGG);
  unsigned* flg = (unsigned*)(ws + WS_FLG);

  __shared__ __align__(16) float sBu[CL * 33];            // 8448B
  __shared__ __align__(16) unsigned short sSt[CL * SD];   // 4096B local-scan states (bf16)
  __shared__ float sPref[SD];
  __shared__ float sL2a[SD];

  const float dtg = 0.001f + 0.099f * (1.f / (1.f + expf(-dt_logit[g])));

  // per-lane-n decay: log2(a_n) = A*dt*log2(e)
  const float l2a_n = -softplus_f(A_log[g * SD + n]) * dtg * 1.44269504f;
  const float a_n = exp2f(l2a_n);
  if (l < SD) sL2a[l] = l2a_n;

  // frac for the two B-operand n's this lane touches (n' = nt*16 + lr)
  float fracv[2];
  #pragma unroll
  for (int nt = 0; nt < 2; ++nt) {
    int np = nt * 16 + lr;
    float A = -softplus_f(A_log[g * SD + np]);
    float a = expf(A * dtg);
    fracv[nt] = (fabsf(A) > 1e-6f) ? (a - 1.f) / A : dtg;
  }

  // B fragments: Bbar[n'][i] = frac * B_param[g][n'][i]
  const float* bp = B_param + (size_t)g * SD * GD;
  short8 bfr[4][2];
  #pragma unroll
  for (int kt = 0; kt < 4; ++kt)
    #pragma unroll
    for (int nt = 0; nt < 2; ++nt) {
      const float* p = bp + (size_t)(nt * 16 + lr) * GD + kt * 32 + lh * 8;
      float4 v0 = *(const float4*)p;
      float4 v1 = *(const float4*)(p + 4);
      float s = fracv[nt];
      v0.x*=s; v0.y*=s; v0.z*=s; v0.w*=s;
      v1.x*=s; v1.y*=s; v1.z*=s; v1.w*=s;
      bfr[kt][nt] = pack8(v0, v1);
    }

  // ---- phase A GEMM: Bu[t][n] = sum_i u[t][i] * Bbar[n][i] ----
  const float* up = u + ((size_t)b * TT + (size_t)c * CL) * DM + g * GD;
  f32x4 acc[4][2];
  #pragma unroll
  for (int m = 0; m < 4; ++m)
    #pragma unroll
    for (int nt = 0; nt < 2; ++nt)
      #pragma unroll
      for (int j = 0; j < 4; ++j) acc[m][nt][j] = 0.f;

  #pragma unroll
  for (int kt = 0; kt < 4; ++kt) {
    short8 af[4];
    #pragma unroll
    for (int m = 0; m < 4; ++m) {
      const float* p = up + (size_t)(m * 16 + lr) * DM + kt * 32 + lh * 8;
      float4 v0 = *(const float4*)p;
      float4 v1 = *(const float4*)(p + 4);
      af[m] = pack8(v0, v1);
    }
    #pragma unroll
    for (int m = 0; m < 4; ++m)
      #pragma unroll
      for (int nt = 0; nt < 2; ++nt)
        acc[m][nt] = __builtin_amdgcn_mfma_f32_16x16x32_bf16(af[m], bfr[kt][nt], acc[m][nt], 0, 0, 0);
  }

  #pragma unroll
  for (int m = 0; m < 4; ++m)
    #pragma unroll
    for (int nt = 0; nt < 2; ++nt)
      #pragma unroll
      for (int j = 0; j < 4; ++j) {
        int t = m * 16 + lh * 4 + j;   // C/D: row=(lane>>4)*4+j, col=lane&15
        sBu[t * 33 + (nt * 16 + lr)] = acc[m][nt][j];
      }
  __syncthreads();

  // ---- local scan (zero entry), states stay in LDS ----
  float s_agg = 0.f;
  if (l < SD) {
    float s = 0.f;
    #pragma unroll
    for (int t = 0; t < CL; ++t) {
      s = fmaf(s, a_n, sBu[t * 33 + l]);
      sSt[t * SD + l] = f2bf(s);
    }
    s_agg = s;
    // publish aggregate (agent scope: visible across XCDs)
    __hip_atomic_store(&agg[(chain * NC + c) * SD + l], s,
                       __ATOMIC_RELAXED, __HIP_MEMORY_SCOPE_AGENT);
  }
  __threadfence();   // wave-wide drain + L2 writeback before flag release
  if (l == 0)
    __hip_atomic_store(&flg[chain * NC + c], 1u,
                       __ATOMIC_RELEASE, __HIP_MEMORY_SCOPE_AGENT);

  // ---- wait for all predecessor chunk aggregates ----
  if (l == 0) {
    for (int j = 0; j < c; ++j)
      while (__hip_atomic_load(&flg[chain * NC + j],
                               __ATOMIC_RELAXED, __HIP_MEMORY_SCOPE_AGENT) == 0)
        __builtin_amdgcn_s_sleep(2);
  }
  __builtin_amdgcn_fence(__ATOMIC_ACQUIRE, "agent");

  // ---- chunk-entry prefix: fixed-order weighted sum (deterministic) ----
  // p = state0 * aL^c + sum_j aL^(c-1-j) * agg_j,  aL^k = exp2(64k*log2 a)
  if (l < SD) {
    const float k64 = 64.f * l2a_n;
    float a0 = 0.f, a1 = 0.f, a2 = 0.f, a3 = 0.f;
    const float* ap = agg + (size_t)chain * NC * SD + n;
    int j = 0;
    for (; j + 4 <= c; j += 4) {
      float w0 = exp2f((float)(c - 1 - j) * k64);
      float w1 = exp2f((float)(c - 2 - j) * k64);
      float w2 = exp2f((float)(c - 3 - j) * k64);
      float w3 = exp2f((float)(c - 4 - j) * k64);
      a0 = fmaf(w0, ap[(size_t)(j + 0) * SD], a0);
      a1 = fmaf(w1, ap[(size_t)(j + 1) * SD], a1);
      a2 = fmaf(w2, ap[(size_t)(j + 2) * SD], a2);
      a3 = fmaf(w3, ap[(size_t)(j + 3) * SD], a3);
    }
    for (; j < c; ++j)
      a0 = fmaf(exp2f((float)(c - 1 - j) * k64), ap[(size_t)j * SD], a0);
    float p = fmaf(state0[chain * SD + n], exp2f((float)c * k64),
                   (a0 + a1) + (a2 + a3));
    sPref[l] = p;
    if (c == NC - 1)
      sfin[chain * SD + l] = fmaf(p, exp2f(k64), s_agg);
  }
  __syncthreads();

  // ---- corrected state fragments (B operand: col=t, k=n) ----
  // s_true[t][n] = s_loc[t][n] + a_n^(t+1) * pref[n];  lane: t=tt*16+lr, n=lh*8+e
  short8 sf[4];
  {
    float pr[8], l2av[8];
    #pragma unroll
    for (int e = 0; e < 8; ++e) { pr[e] = sPref[lh * 8 + e]; l2av[e] = sL2a[lh * 8 + e]; }
    #pragma unroll
    for (int tt = 0; tt < 4; ++tt) {
      int t = tt * 16 + lr;
      short8 sl = *(const short8*)(sSt + t * SD + lh * 8);
      short8 hh;
      #pragma unroll
      for (int e = 0; e < 8; ++e) {
        float w = exp2f((float)(t + 1) * l2av[e]);
        hh[e] = (short)f2bf(fmaf(w, pr[e], bf2f((unsigned short)sl[e])));
      }
      sf[tt] = hh;
    }
  }

  // ---- C GEMM (swapped operands): D[d][t] = sum_n C[d][n]*s[t][n] ----
  const float* cp = C + (size_t)g * GD * SD;
  const size_t rowbase = ((size_t)b * TT + (size_t)c * CL) * DM + g * GD;

  #pragma unroll
  for (int h = 0; h < 2; ++h) {
    short8 cf[4];
    #pragma unroll
    for (int dd = 0; dd < 4; ++dd) {
      int d = (h * 4 + dd) * 16 + lr;
      const float* pp = cp + (size_t)d * SD + lh * 8;
      float4 v0 = *(const float4*)pp;
      float4 v1 = *(const float4*)(pp + 4);
      cf[dd] = pack8(v0, v1);
    }
    f32x4 acc2[4][4];
    #pragma unroll
    for (int dd = 0; dd < 4; ++dd)
      #pragma unroll
      for (int tt = 0; tt < 4; ++tt) {
        f32x4 z;
        #pragma unroll
        for (int j = 0; j < 4; ++j) z[j] = 0.f;
        acc2[dd][tt] = __builtin_amdgcn_mfma_f32_16x16x32_bf16(cf[dd], sf[tt], z, 0, 0, 0);
      }
    // epilogue: y = Cs + Dp*u (u re-read; L2/L3-hot from phase A)
    #pragma unroll
    for (int dd = 0; dd < 4; ++dd) {
      int d0 = (h * 4 + dd) * 16 + lh * 4;
      float4 dp4 = *(const float4*)(Dp + g * GD + d0);
      #pragma unroll
      for (int tt = 0; tt < 4; ++tt) {
        int t = tt * 16 + lr;
        size_t off = rowbase + (size_t)t * DM + d0;
        float4 u4 = *(const float4*)(u + off);
        float4 r;
        r.x = acc2[dd][tt][0] + dp4.x * u4.x;
        r.y = acc2[dd][tt][1] + dp4.y * u4.y;
        r.z = acc2[dd][tt][2] + dp4.z * u4.z;
        r.w = acc2[dd][tt][3] + dp4.w * u4.w;
        *(float4*)(y + off) = r;
      }
    }
  }
}

extern "C" void kernel_launch(void* const* d_in, const int* in_sizes, int n_in,
                              void* d_out, int out_size, void* d_ws, size_t ws_size,
                              hipStream_t stream) {
  const float* u       = (const float*)d_in[0];
  const float* state0  = (const float*)d_in[1];
  const float* A_log   = (const float*)d_in[2];
  const float* B_param = (const float*)d_in[3];
  const float* C       = (const float*)d_in[4];
  const float* Dp      = (const float*)d_in[5];
  const float* dtl     = (const float*)d_in[6];
  float* y = (float*)d_out;
  unsigned char* ws = (unsigned char*)d_ws;
  float* sfin = y + (size_t)BS * TT * DM;

  // zero the carry flags (graph-capturable memset node); stream-ordered before kernel
  hipMemsetAsync(ws + WS_FLG, 0, NCHAIN * NC * sizeof(unsigned), stream);
  fused_s5<<<dim3(BS * NG * NC), dim3(64), 0, stream>>>(u, state0, A_log, B_param, C, Dp, dtl, ws, y, sfin);
}

// Round 7
// 47.134 us; speedup vs baseline: 3.0854x; 3.0854x over previous
//
#include <hip/hip_runtime.h>
#include <hip/hip_bf16.h>

#define DM 1024
#define SD 32
#define NG 8
#define GD 128
#define BS 4
#define TT 4096
#define CL 64        // chunk length
#define NC (TT/CL)   // 64 chunks

typedef __attribute__((ext_vector_type(8))) short short8;
typedef __attribute__((ext_vector_type(4))) float f32x4;

// workspace layout (bytes), 16B aligned
#define WS_POWA  0                         // f32[8][64][32]  = 64KB  (powA[g][t][n] = Abar^(t+1))
#define WS_STL   65536                     // bf16[4][64][8][64][32] = 8MB (local-scan states)
#define WS_CARRY (WS_STL + 8388608)        // f32[4][64][8][32] = 256KB
#define WS_PAL   (WS_CARRY + 262144)       // f32[8][64][32] = 64KB (powAL[g][j][n] = (a^64)^j)

__device__ __forceinline__ unsigned short f2bf(float f) {
  __hip_bfloat16 h = __float2bfloat16(f);
  return __builtin_bit_cast(unsigned short, h);
}
__device__ __forceinline__ float bf2f(unsigned short h) {
  return __uint_as_float(((unsigned)h) << 16);
}
__device__ __forceinline__ float softplus_f(float x) {
  return (x > 20.f) ? x : log1pf(expf(x));
}
__device__ __forceinline__ short8 pack8(float4 a, float4 b) {
  short8 h;
  h[0]=(short)f2bf(a.x); h[1]=(short)f2bf(a.y); h[2]=(short)f2bf(a.z); h[3]=(short)f2bf(a.w);
  h[4]=(short)f2bf(b.x); h[5]=(short)f2bf(b.y); h[6]=(short)f2bf(b.z); h[7]=(short)f2bf(b.w);
  return h;
}

// ---------------- KA: u via global_load_lds (swizzled src) + Bu GEMM + local scan ----------------
__global__ __launch_bounds__(64) void ka_bu_scan(const float* __restrict__ u,
                                                 const float* __restrict__ A_log,
                                                 const float* __restrict__ B_param,
                                                 const float* __restrict__ dt_logit,
                                                 unsigned char* __restrict__ ws) {
  const int bx = blockIdx.x;
  const int c = bx & (NC - 1);
  const int g = (bx >> 6) & (NG - 1);
  const int b = bx >> 9;
  const int l = threadIdx.x;
  const int lr = l & 15, lh = l >> 4;

  // 32KB: u tile f32 [64][128], XOR-swizzled (16B granule, mask=(row&7)<<4).
  // After the MFMA loop the front 12.5KB is reused for sBu/sSt.
  __shared__ __align__(16) unsigned char sMem[32768];

  // ---- issue async staging: 32 x global_load_lds dwordx4, pre-swizzled source ----
  // LDS linear offset o = s*1024 + lane*16 holds u[row=o>>9][byte (o&511)^((row&7)<<4)]
  {
    const char* upB = (const char*)(u + ((size_t)b * TT + (size_t)c * CL) * DM + g * GD);
    const int h = l >> 5;
    const int col16 = (l & 31) * 16;
    #pragma unroll
    for (int s = 0; s < 32; ++s) {
      const int row = 2 * s + h;
      const int swz = (row & 7) << 4;
      const char* gsrc = upB + (size_t)row * (DM * 4) + (col16 ^ swz);
      __builtin_amdgcn_global_load_lds(
          (const __attribute__((address_space(1))) unsigned int*)gsrc,
          (__attribute__((address_space(3))) unsigned int*)(sMem + s * 1024),
          16, 0, 0);
    }
  }

  const float dtg = 0.001f + 0.099f * (1.f / (1.f + expf(-dt_logit[g])));

  // frac for the two B-operand n's this lane touches (n = nt*16 + lr)
  float fracv[2];
  #pragma unroll
  for (int nt = 0; nt < 2; ++nt) {
    int n = nt * 16 + lr;
    float A = -softplus_f(A_log[g * SD + n]);
    float a = expf(A * dtg);
    fracv[nt] = (fabsf(A) > 1e-6f) ? (a - 1.f) / A : dtg;
  }
  // scan decay for n = l&31
  float a_scan;
  {
    float A = -softplus_f(A_log[g * SD + (l & 31)]);
    a_scan = expf(A * dtg);
  }

  // B fragments (tiny, L2-hot): Bbar[n][i] = frac_n * B_param[g][n][i]
  const float* bp = B_param + (size_t)g * SD * GD;
  short8 bfr[4][2];
  #pragma unroll
  for (int kt = 0; kt < 4; ++kt)
    #pragma unroll
    for (int nt = 0; nt < 2; ++nt) {
      const float* p = bp + (size_t)(nt * 16 + lr) * GD + kt * 32 + lh * 8;
      float4 v0 = *(const float4*)p;
      float4 v1 = *(const float4*)(p + 4);
      float s = fracv[nt];
      v0.x*=s; v0.y*=s; v0.z*=s; v0.w*=s;
      v1.x*=s; v1.y*=s; v1.z*=s; v1.w*=s;
      bfr[kt][nt] = pack8(v0, v1);
    }

  // ---- wait staging, then fragments from LDS (swizzled read, ~2-way conflicts) ----
  asm volatile("s_waitcnt vmcnt(0)" ::: "memory");
  __builtin_amdgcn_sched_barrier(0);

  f32x4 acc[4][2];
  #pragma unroll
  for (int m = 0; m < 4; ++m)
    #pragma unroll
    for (int nt = 0; nt < 2; ++nt)
      #pragma unroll
      for (int j = 0; j < 4; ++j) acc[m][nt][j] = 0.f;

  #pragma unroll
  for (int kt = 0; kt < 4; ++kt) {
    short8 af[4];
    #pragma unroll
    for (int m = 0; m < 4; ++m) {
      const int row = m * 16 + lr;
      const int rb = row * 512;
      const int cs = (row & 7) << 4;
      const int c0 = kt * 128 + lh * 32;
      float4 v0 = *(const float4*)(sMem + rb + (c0 ^ cs));
      float4 v1 = *(const float4*)(sMem + rb + ((c0 + 16) ^ cs));
      af[m] = pack8(v0, v1);
    }
    #pragma unroll
    for (int m = 0; m < 4; ++m)
      #pragma unroll
      for (int nt = 0; nt < 2; ++nt)
        acc[m][nt] = __builtin_amdgcn_mfma_f32_16x16x32_bf16(af[m], bfr[kt][nt], acc[m][nt], 0, 0, 0);
  }
  __syncthreads();   // single wave: cheap; orders sU reads before overlay writes

  // overlay: Bu f32 [64][33] then states bf16 [64][32]
  float* sBu = (float*)sMem;                           // 8448B
  unsigned short* sSt = (unsigned short*)(sMem + 8448); // 4096B
  #pragma unroll
  for (int m = 0; m < 4; ++m)
    #pragma unroll
    for (int nt = 0; nt < 2; ++nt)
      #pragma unroll
      for (int j = 0; j < 4; ++j) {
        int t = m * 16 + lh * 4 + j;   // C/D: row=(lane>>4)*4+j, col=lane&15
        sBu[t * 33 + (nt * 16 + lr)] = acc[m][nt][j];
      }
  __syncthreads();

  float* carry = (float*)(ws + WS_CARRY);
  if (l < SD) {
    float s = 0.f;
    #pragma unroll
    for (int t = 0; t < CL; ++t) {
      s = fmaf(s, a_scan, sBu[t * 33 + l]);
      sSt[t * SD + l] = f2bf(s);
    }
    carry[((b * NC + c) * NG + g) * SD + l] = s;
  }
  __syncthreads();

  // states -> global (bf16), coalesced
  unsigned short* stg = (unsigned short*)(ws + WS_STL) + ((size_t)((b * NC + c) * NG + g)) * CL * SD;
  #pragma unroll
  for (int p = 0; p < 4; ++p) {
    int off = (p * 64 + l) * 8;        // 2048 ushorts
    *(short8*)(stg + off) = *(short8*)(sSt + off);
  }

  // 8 special blocks (b==0,c==0) emit powA and powAL tables for KB
  if (b == 0 && c == 0 && l < SD) {
    float* powA = (float*)(ws + WS_POWA);
    float* powAL = (float*)(ws + WS_PAL);
    float p = 1.f;
    #pragma unroll
    for (int t = 0; t < CL; ++t) {
      p *= a_scan;
      powA[(g * CL + t) * SD + l] = p;
    }
    float aL = p;                       // a^64
    float q = 1.f;
    #pragma unroll
    for (int j = 0; j < CL; ++j) {
      powAL[(g * CL + j) * SD + l] = q; // aL^j, j=0 -> 1
      q *= aL;
    }
  }
}

// ---------------- KB: parallel prefix + correction + C GEMM + (Dp*u if Dp!=0) + y ----------------
__global__ __launch_bounds__(64) void kb_y(const float* __restrict__ u,
                                           const float* __restrict__ state0,
                                           const float* __restrict__ C,
                                           const float* __restrict__ Dp,
                                           unsigned char* __restrict__ ws,
                                           float* __restrict__ y,
                                           float* __restrict__ sfin) {
  const int bx = blockIdx.x;
  const int c = bx & (NC - 1);
  const int g = (bx >> 6) & (NG - 1);
  const int b = bx >> 9;
  const int l = threadIdx.x;
  const int lr = l & 15, lh = l >> 4;
  const int n = l & 31;

  const float* powA = (const float*)(ws + WS_POWA) + g * CL * SD;
  const float* powAL = (const float*)(ws + WS_PAL) + g * CL * SD;
  const float* carry = (const float*)(ws + WS_CARRY);
  const unsigned short* stg = (const unsigned short*)(ws + WS_STL) + ((size_t)((b * NC + c) * NG + g)) * CL * SD;

  // Dp==0 detection (wave-uniform): skip the 64MB u re-read when the D-term vanishes.
  bool need_u;
  {
    float2 dpc = *(const float2*)(Dp + g * GD + l * 2);
    need_u = __ballot((dpc.x != 0.f) || (dpc.y != 0.f)) != 0ULL;
  }

  // --- chunk-entry prefix: p = state0*aL^c + sum_{cc<c} aL^(c-1-cc)*carry_cc ---
  float p;
  {
    float a0 = 0.f, a1 = 0.f, a2 = 0.f, a3 = 0.f;
    int cc = 0;
    while (cc + 8 <= c) {
      float ca[8], w[8];
      #pragma unroll
      for (int e = 0; e < 8; ++e) {
        ca[e] = carry[((b * NC + cc + e) * NG + g) * SD + n];
        w[e]  = powAL[(c - 1 - cc - e) * SD + n];
      }
      a0 = fmaf(w[0], ca[0], a0); a1 = fmaf(w[1], ca[1], a1);
      a2 = fmaf(w[2], ca[2], a2); a3 = fmaf(w[3], ca[3], a3);
      a0 = fmaf(w[4], ca[4], a0); a1 = fmaf(w[5], ca[5], a1);
      a2 = fmaf(w[6], ca[6], a2); a3 = fmaf(w[7], ca[7], a3);
      cc += 8;
    }
    for (; cc < c; ++cc)
      a0 = fmaf(powAL[(c - 1 - cc) * SD + n], carry[((b * NC + cc) * NG + g) * SD + n], a0);
    p = fmaf(state0[(b * NG + g) * SD + n], powAL[c * SD + n], (a0 + a1) + (a2 + a3));
  }
  __shared__ float sPref[SD];
  if (l < SD) sPref[l] = p;
  if (c == NC - 1 && l < SD) {
    const float aL = powA[(CL - 1) * SD + l];
    sfin[(b * NG + g) * SD + l] = fmaf(p, aL, carry[((b * NC + (NC - 1)) * NG + g) * SD + l]);
  }
  __syncthreads();

  // --- corrected state fragments (B operand, col = t, k = n) ---
  short8 sf[4];
  {
    float pr[8];
    #pragma unroll
    for (int e = 0; e < 8; ++e) pr[e] = sPref[lh * 8 + e];
    #pragma unroll
    for (int tt = 0; tt < 4; ++tt) {
      int t = tt * 16 + lr;
      short8 sl = *(const short8*)(stg + t * SD + lh * 8);
      const float* pw = powA + t * SD + lh * 8;
      float4 pw0 = *(const float4*)pw;
      float4 pw1 = *(const float4*)(pw + 4);
      short8 hh;
      hh[0] = (short)f2bf(bf2f((unsigned short)sl[0]) + pw0.x * pr[0]);
      hh[1] = (short)f2bf(bf2f((unsigned short)sl[1]) + pw0.y * pr[1]);
      hh[2] = (short)f2bf(bf2f((unsigned short)sl[2]) + pw0.z * pr[2]);
      hh[3] = (short)f2bf(bf2f((unsigned short)sl[3]) + pw0.w * pr[3]);
      hh[4] = (short)f2bf(bf2f((unsigned short)sl[4]) + pw1.x * pr[4]);
      hh[5] = (short)f2bf(bf2f((unsigned short)sl[5]) + pw1.y * pr[5]);
      hh[6] = (short)f2bf(bf2f((unsigned short)sl[6]) + pw1.z * pr[6]);
      hh[7] = (short)f2bf(bf2f((unsigned short)sl[7]) + pw1.w * pr[7]);
      sf[tt] = hh;
    }
  }

  // --- GEMM with swapped operands: D[d][t] = sum_n C[d][n] * s[t][n] ---
  const float* cp = C + (size_t)g * GD * SD;
  const size_t rowbase = ((size_t)b * TT + (size_t)c * CL) * DM + g * GD;

  #pragma unroll
  for (int h = 0; h < 2; ++h) {
    short8 cf[4];
    #pragma unroll
    for (int dd = 0; dd < 4; ++dd) {
      int d = (h * 4 + dd) * 16 + lr;
      const float* pp = cp + (size_t)d * SD + lh * 8;
      float4 v0 = *(const float4*)pp;
      float4 v1 = *(const float4*)(pp + 4);
      cf[dd] = pack8(v0, v1);
    }
    f32x4 acc[4][4];
    #pragma unroll
    for (int dd = 0; dd < 4; ++dd)
      #pragma unroll
      for (int tt = 0; tt < 4; ++tt) {
        f32x4 z;
        #pragma unroll
        for (int j = 0; j < 4; ++j) z[j] = 0.f;
        acc[dd][tt] = __builtin_amdgcn_mfma_f32_16x16x32_bf16(cf[dd], sf[tt], z, 0, 0, 0);
      }
    // epilogue: y = Cs (+ Dp*u only when Dp != 0), vectorized float4
    #pragma unroll
    for (int dd = 0; dd < 4; ++dd) {
      int d0 = (h * 4 + dd) * 16 + lh * 4;
      float4 dp4 = *(const float4*)(Dp + g * GD + d0);
      #pragma unroll
      for (int tt = 0; tt < 4; ++tt) {
        int t = tt * 16 + lr;
        size_t off = rowbase + (size_t)t * DM + d0;
        float4 r;
        r.x = acc[dd][tt][0]; r.y = acc[dd][tt][1];
        r.z = acc[dd][tt][2]; r.w = acc[dd][tt][3];
        if (need_u) {
          float4 u4 = *(const float4*)(u + off);
          r.x += dp4.x * u4.x; r.y += dp4.y * u4.y;
          r.z += dp4.z * u4.z; r.w += dp4.w * u4.w;
        }
        *(float4*)(y + off) = r;
      }
    }
  }
}

extern "C" void kernel_launch(void* const* d_in, const int* in_sizes, int n_in,
                              void* d_out, int out_size, void* d_ws, size_t ws_size,
                              hipStream_t stream) {
  const float* u       = (const float*)d_in[0];
  const float* state0  = (const float*)d_in[1];
  const float* A_log   = (const float*)d_in[2];
  const float* B_param = (const float*)d_in[3];
  const float* C       = (const float*)d_in[4];
  const float* Dp      = (const float*)d_in[5];
  const float* dtl     = (const float*)d_in[6];
  float* y = (float*)d_out;
  unsigned char* ws = (unsigned char*)d_ws;
  float* sfin = y + (size_t)BS * TT * DM;

  ka_bu_scan<<<dim3(BS * NG * NC), dim3(64), 0, stream>>>(u, A_log, B_param, dtl, ws);
  kb_y<<<dim3(BS * NG * NC), dim3(64), 0, stream>>>(u, state0, C, Dp, ws, y, sfin);
}

// Round 8
// 45.875 us; speedup vs baseline: 3.1700x; 1.0274x over previous
//
#include <hip/hip_runtime.h>
#include <hip/hip_bf16.h>

#define DM 1024
#define SD 32
#define NG 8
#define GD 128
#define BS 4
#define TT 4096
#define CL 64        // chunk length
#define NC (TT/CL)   // 64 chunks

typedef __attribute__((ext_vector_type(8))) short short8;
typedef __attribute__((ext_vector_type(4))) float f32x4;

// workspace layout (bytes), 16B aligned
#define WS_POWA  0                         // f32[8][64][32]  = 64KB  (powA[g][t][n] = Abar^(t+1))
#define WS_STL   65536                     // bf16[4][64][8][64][32] = 8MB (local-scan states)
#define WS_CARRY (WS_STL + 8388608)        // f32[4][8][64][32] = 256KB, layout [b][g][c][n]
#define WS_PAL   (WS_CARRY + 262144)       // f32[8][64][32] = 64KB (powAL[g][j][n] = (a^64)^j)

__device__ __forceinline__ unsigned short f2bf(float f) {
  __hip_bfloat16 h = __float2bfloat16(f);
  return __builtin_bit_cast(unsigned short, h);
}
__device__ __forceinline__ float bf2f(unsigned short h) {
  return __uint_as_float(((unsigned)h) << 16);
}
__device__ __forceinline__ float softplus_f(float x) {
  return (x > 20.f) ? x : log1pf(expf(x));
}
__device__ __forceinline__ short8 pack8(float4 a, float4 b) {
  short8 h;
  h[0]=(short)f2bf(a.x); h[1]=(short)f2bf(a.y); h[2]=(short)f2bf(a.z); h[3]=(short)f2bf(a.w);
  h[4]=(short)f2bf(b.x); h[5]=(short)f2bf(b.y); h[6]=(short)f2bf(b.z); h[7]=(short)f2bf(b.w);
  return h;
}

// ---------------- KA: reg-pipelined Bu GEMM + local scan (LDS only for Bu/state handoff) ----------------
__global__ __launch_bounds__(64) void ka_bu_scan(const float* __restrict__ u,
                                                 const float* __restrict__ A_log,
                                                 const float* __restrict__ B_param,
                                                 const float* __restrict__ dt_logit,
                                                 unsigned char* __restrict__ ws) {
  const int bx = blockIdx.x;
  const int c = bx & (NC - 1);
  const int g = (bx >> 6) & (NG - 1);
  const int b = bx >> 9;
  const int l = threadIdx.x;
  const int lr = l & 15, lh = l >> 4;

  const float dtg = 0.001f + 0.099f * (1.f / (1.f + expf(-dt_logit[g])));

  float fracv[2];
  #pragma unroll
  for (int nt = 0; nt < 2; ++nt) {
    int n = nt * 16 + lr;
    float A = -softplus_f(A_log[g * SD + n]);
    float a = expf(A * dtg);
    fracv[nt] = (fabsf(A) > 1e-6f) ? (a - 1.f) / A : dtg;
  }
  float a_scan;
  {
    float A = -softplus_f(A_log[g * SD + (l & 31)]);
    a_scan = expf(A * dtg);
  }

  // B fragment loads (issued first; small, L2-hot)
  const float* bp = B_param + (size_t)g * SD * GD;
  short8 bfr[4][2];
  #pragma unroll
  for (int kt = 0; kt < 4; ++kt)
    #pragma unroll
    for (int nt = 0; nt < 2; ++nt) {
      const float* p = bp + (size_t)(nt * 16 + lr) * GD + kt * 32 + lh * 8;
      float4 v0 = *(const float4*)p;
      float4 v1 = *(const float4*)(p + 4);
      float s = fracv[nt];
      v0.x*=s; v0.y*=s; v0.z*=s; v0.w*=s;
      v1.x*=s; v1.y*=s; v1.z*=s; v1.w*=s;
      bfr[kt][nt] = pack8(v0, v1);
    }

  // u fragments: 2-deep kt pipeline through registers (8KB/wave in flight)
  const float* up = u + ((size_t)b * TT + (size_t)c * CL) * DM + g * GD;
  float4 ub[2][4][2];
  #pragma unroll
  for (int kt = 0; kt < 2; ++kt)
    #pragma unroll
    for (int m = 0; m < 4; ++m) {
      const float* p = up + (size_t)(m * 16 + lr) * DM + kt * 32 + lh * 8;
      ub[kt][m][0] = *(const float4*)p;
      ub[kt][m][1] = *(const float4*)(p + 4);
    }

  f32x4 acc[4][2];
  #pragma unroll
  for (int m = 0; m < 4; ++m)
    #pragma unroll
    for (int nt = 0; nt < 2; ++nt)
      #pragma unroll
      for (int j = 0; j < 4; ++j) acc[m][nt][j] = 0.f;

  #pragma unroll
  for (int kt = 0; kt < 4; ++kt) {
    short8 af[4];
    #pragma unroll
    for (int m = 0; m < 4; ++m)
      af[m] = pack8(ub[kt & 1][m][0], ub[kt & 1][m][1]);
    if (kt < 2) {   // prefetch kt+2 into the buffer just consumed
      #pragma unroll
      for (int m = 0; m < 4; ++m) {
        const float* p = up + (size_t)(m * 16 + lr) * DM + (kt + 2) * 32 + lh * 8;
        ub[kt & 1][m][0] = *(const float4*)p;
        ub[kt & 1][m][1] = *(const float4*)(p + 4);
      }
    }
    #pragma unroll
    for (int m = 0; m < 4; ++m)
      #pragma unroll
      for (int nt = 0; nt < 2; ++nt)
        acc[m][nt] = __builtin_amdgcn_mfma_f32_16x16x32_bf16(af[m], bfr[kt][nt], acc[m][nt], 0, 0, 0);
  }

  // hand Bu to the scan via LDS (12.5KB total -> 8 blocks/CU)
  __shared__ __align__(16) float sBu[CL * 33];            // 8448B
  __shared__ __align__(16) unsigned short sSt[CL * SD];   // 4096B
  #pragma unroll
  for (int m = 0; m < 4; ++m)
    #pragma unroll
    for (int nt = 0; nt < 2; ++nt)
      #pragma unroll
      for (int j = 0; j < 4; ++j) {
        int t = m * 16 + lh * 4 + j;   // C/D: row=(lane>>4)*4+j, col=lane&15
        sBu[t * 33 + (nt * 16 + lr)] = acc[m][nt][j];
      }
  __syncthreads();

  float* carry = (float*)(ws + WS_CARRY);
  if (l < SD) {
    float s = 0.f;
    #pragma unroll
    for (int t = 0; t < CL; ++t) {
      s = fmaf(s, a_scan, sBu[t * 33 + l]);
      sSt[t * SD + l] = f2bf(s);
    }
    carry[((b * NG + g) * NC + c) * SD + l] = s;   // [b][g][c][n]
  }
  __syncthreads();

  // states -> global (bf16), coalesced
  unsigned short* stg = (unsigned short*)(ws + WS_STL) + ((size_t)((b * NC + c) * NG + g)) * CL * SD;
  #pragma unroll
  for (int p = 0; p < 4; ++p) {
    int off = (p * 64 + l) * 8;        // 2048 ushorts
    *(short8*)(stg + off) = *(short8*)(sSt + off);
  }

  // 8 special blocks (b==0,c==0) emit powA and powAL tables for KB
  if (b == 0 && c == 0 && l < SD) {
    float* powA = (float*)(ws + WS_POWA);
    float* powAL = (float*)(ws + WS_PAL);
    float p = 1.f;
    #pragma unroll
    for (int t = 0; t < CL; ++t) {
      p *= a_scan;
      powA[(g * CL + t) * SD + l] = p;
    }
    float aL = p;                       // a^64
    float q = 1.f;
    #pragma unroll
    for (int j = 0; j < CL; ++j) {
      powAL[(g * CL + j) * SD + l] = q; // aL^j, j=0 -> 1
      q *= aL;
    }
  }
}

// ---------------- KB: 2-wave d-split; prefix per wave; shfl-broadcast; C GEMM + y ----------------
__global__ __launch_bounds__(128) void kb_y(const float* __restrict__ u,
                                            const float* __restrict__ state0,
                                            const float* __restrict__ C,
                                            const float* __restrict__ Dp,
                                            unsigned char* __restrict__ ws,
                                            float* __restrict__ y,
                                            float* __restrict__ sfin) {
  const int bx = blockIdx.x;
  const int c = bx & (NC - 1);
  const int g = (bx >> 6) & (NG - 1);
  const int b = bx >> 9;
  const int tid = threadIdx.x;
  const int w = tid >> 6;          // wave 0..1 -> d-half
  const int l = tid & 63;
  const int lr = l & 15, lh = l >> 4;
  const int n = l & 31;

  const float* powA = (const float*)(ws + WS_POWA) + g * CL * SD;
  const float* powAL = (const float*)(ws + WS_PAL) + g * CL * SD;
  const float* carry = (const float*)(ws + WS_CARRY) + (size_t)(b * NG + g) * NC * SD;  // [c][n]
  const unsigned short* stg = (const unsigned short*)(ws + WS_STL) + ((size_t)((b * NC + c) * NG + g)) * CL * SD;

  // Dp==0 detection (wave-uniform): skip the u re-read when the D-term vanishes.
  bool need_u;
  {
    float2 dpc = *(const float2*)(Dp + g * GD + l * 2);
    need_u = __ballot((dpc.x != 0.f) || (dpc.y != 0.f)) != 0ULL;
  }

  // --- chunk-entry prefix (per wave, redundant): p = state0*aL^c + sum aL^(c-1-cc)*carry_cc ---
  float p;
  {
    float a0 = 0.f, a1 = 0.f, a2 = 0.f, a3 = 0.f;
    int cc = 0;
    while (cc + 8 <= c) {
      float ca[8], wt[8];
      #pragma unroll
      for (int e = 0; e < 8; ++e) {
        ca[e] = carry[(cc + e) * SD + n];
        wt[e] = powAL[(c - 1 - cc - e) * SD + n];
      }
      a0 = fmaf(wt[0], ca[0], a0); a1 = fmaf(wt[1], ca[1], a1);
      a2 = fmaf(wt[2], ca[2], a2); a3 = fmaf(wt[3], ca[3], a3);
      a0 = fmaf(wt[4], ca[4], a0); a1 = fmaf(wt[5], ca[5], a1);
      a2 = fmaf(wt[6], ca[6], a2); a3 = fmaf(wt[7], ca[7], a3);
      cc += 8;
    }
    for (; cc < c; ++cc)
      a0 = fmaf(powAL[(c - 1 - cc) * SD + n], carry[cc * SD + n], a0);
    p = fmaf(state0[(b * NG + g) * SD + n], powAL[c * SD + n], (a0 + a1) + (a2 + a3));
  }
  if (w == 0 && c == NC - 1 && l < SD) {
    const float aL = powA[(CL - 1) * SD + l];
    sfin[(b * NG + g) * SD + l] = fmaf(p, aL, carry[(NC - 1) * SD + l]);
  }

  // broadcast pref across the wave (no LDS): pr[e] = p at lane lh*8+e
  float pr[8];
  #pragma unroll
  for (int e = 0; e < 8; ++e) pr[e] = __shfl(p, lh * 8 + e);

  // --- corrected state fragments (B operand, col = t, k = n) ---
  short8 sf[4];
  #pragma unroll
  for (int tt = 0; tt < 4; ++tt) {
    int t = tt * 16 + lr;
    short8 sl = *(const short8*)(stg + t * SD + lh * 8);
    const float* pw = powA + t * SD + lh * 8;
    float4 pw0 = *(const float4*)pw;
    float4 pw1 = *(const float4*)(pw + 4);
    short8 hh;
    hh[0] = (short)f2bf(bf2f((unsigned short)sl[0]) + pw0.x * pr[0]);
    hh[1] = (short)f2bf(bf2f((unsigned short)sl[1]) + pw0.y * pr[1]);
    hh[2] = (short)f2bf(bf2f((unsigned short)sl[2]) + pw0.z * pr[2]);
    hh[3] = (short)f2bf(bf2f((unsigned short)sl[3]) + pw0.w * pr[3]);
    hh[4] = (short)f2bf(bf2f((unsigned short)sl[4]) + pw1.x * pr[4]);
    hh[5] = (short)f2bf(bf2f((unsigned short)sl[5]) + pw1.y * pr[5]);
    hh[6] = (short)f2bf(bf2f((unsigned short)sl[6]) + pw1.z * pr[6]);
    hh[7] = (short)f2bf(bf2f((unsigned short)sl[7]) + pw1.w * pr[7]);
    sf[tt] = hh;
  }

  // --- GEMM (swapped): D[d][t] = sum_n C[d][n]*s[t][n]; wave w owns d-half w ---
  const float* cp = C + (size_t)g * GD * SD;
  const size_t rowbase = ((size_t)b * TT + (size_t)c * CL) * DM + g * GD;

  short8 cf[4];
  #pragma unroll
  for (int dd = 0; dd < 4; ++dd) {
    int d = (w * 4 + dd) * 16 + lr;
    const float* pp = cp + (size_t)d * SD + lh * 8;
    float4 v0 = *(const float4*)pp;
    float4 v1 = *(const float4*)(pp + 4);
    cf[dd] = pack8(v0, v1);
  }
  f32x4 acc[4][4];
  #pragma unroll
  for (int dd = 0; dd < 4; ++dd)
    #pragma unroll
    for (int tt = 0; tt < 4; ++tt) {
      f32x4 z;
      #pragma unroll
      for (int j = 0; j < 4; ++j) z[j] = 0.f;
      acc[dd][tt] = __builtin_amdgcn_mfma_f32_16x16x32_bf16(cf[dd], sf[tt], z, 0, 0, 0);
    }

  // epilogue: y = Cs (+ Dp*u only when Dp != 0), vectorized float4
  #pragma unroll
  for (int dd = 0; dd < 4; ++dd) {
    int d0 = (w * 4 + dd) * 16 + lh * 4;
    float4 dp4 = *(const float4*)(Dp + g * GD + d0);
    #pragma unroll
    for (int tt = 0; tt < 4; ++tt) {
      int t = tt * 16 + lr;
      size_t off = rowbase + (size_t)t * DM + d0;
      float4 r;
      r.x = acc[dd][tt][0]; r.y = acc[dd][tt][1];
      r.z = acc[dd][tt][2]; r.w = acc[dd][tt][3];
      if (need_u) {
        float4 u4 = *(const float4*)(u + off);
        r.x += dp4.x * u4.x; r.y += dp4.y * u4.y;
        r.z += dp4.z * u4.z; r.w += dp4.w * u4.w;
      }
      *(float4*)(y + off) = r;
    }
  }
}

extern "C" void kernel_launch(void* const* d_in, const int* in_sizes, int n_in,
                              void* d_out, int out_size, void* d_ws, size_t ws_size,
                              hipStream_t stream) {
  const float* u       = (const float*)d_in[0];
  const float* state0  = (const float*)d_in[1];
  const float* A_log   = (const float*)d_in[2];
  const float* B_param = (const float*)d_in[3];
  const float* C       = (const float*)d_in[4];
  const float* Dp      = (const float*)d_in[5];
  const float* dtl     = (const float*)d_in[6];
  float* y = (float*)d_out;
  unsigned char* ws = (unsigned char*)d_ws;
  float* sfin = y + (size_t)BS * TT * DM;

  ka_bu_scan<<<dim3(BS * NG * NC), dim3(64), 0, stream>>>(u, A_log, B_param, dtl, ws);
  kb_y<<<dim3(BS * NG * NC), dim3(128), 0, stream>>>(u, state0, C, Dp, ws, y, sfin);
}